// Round 4
// baseline (518.972 us; speedup 1.0000x reference)
//
#include <hip/hip_runtime.h>

typedef __bf16 bf16x8 __attribute__((ext_vector_type(8)));
typedef float f32x4 __attribute__((ext_vector_type(4)));
typedef unsigned int u32x4 __attribute__((ext_vector_type(4)));
typedef unsigned short u16;

#define MFMA16(A, B, C) __builtin_amdgcn_mfma_f32_16x16x32_bf16((A), (B), (C), 0, 0, 0)

#define KEXP   (0.17677669529663687f * 1.4426950408889634f)
#define LOG2E  1.4426950408889634f
#define LAMI   0.35550906759096926f           // LAMBDA_INIT = 0.8 - 0.6*exp(-0.3)
#define ONEML  0.6444909324090307f            // 1 - LAMBDA_INIT

static __device__ __forceinline__ u16 bf16b(float v) {
  __bf16 b = (__bf16)v;
  return __builtin_bit_cast(u16, b);
}

static __device__ __forceinline__ bf16x8 f32frag(const float* p) {
  float4 a = *(const float4*)p;
  float4 b = *(const float4*)(p + 4);
  bf16x8 r;
  r[0] = (__bf16)a.x; r[1] = (__bf16)a.y; r[2] = (__bf16)a.z; r[3] = (__bf16)a.w;
  r[4] = (__bf16)b.x; r[5] = (__bf16)b.y; r[6] = (__bf16)b.z; r[7] = (__bf16)b.w;
  return r;
}

// ---------------- sigma -> s_val [B,H,L] ----------------
// 2048 blocks x 256: block = one token, 16 groups of 16 lanes = 16 heads.
// 8192 waves (32/CU) vs previous 512 (2/CU): latency-hiding fix.
__global__ __launch_bounds__(256) void sigma_kernel(const float* __restrict__ q,
                                                    const float* __restrict__ Ws,
                                                    const float* __restrict__ bsig,
                                                    float* __restrict__ s_val) {
  int tok = blockIdx.x;
  int h = threadIdx.x >> 4;
  int l = threadIdx.x & 15;
  const float* qr = q + (size_t)tok * 1024;
  const float* wr = Ws + (size_t)h * 1024;
  float acc = 0.f;
#pragma unroll 4
  for (int c = 0; c < 16; ++c) {
    float4 a = *(const float4*)(qr + c * 64 + l * 4);
    float4 b = *(const float4*)(wr + c * 64 + l * 4);
    acc += a.x * b.x + a.y * b.y + a.z * b.z + a.w * b.w;
  }
  acc += __shfl_xor(acc, 1); acc += __shfl_xor(acc, 2);
  acc += __shfl_xor(acc, 4); acc += __shfl_xor(acc, 8);
  if (l == 0) {
    float sg = acc + bsig[h];
    float sig = 1.f / (1.f + __expf(-5.f * sg));
    float sv = exp2f(1.5849625007211562f * (sig + 1e-5f)) - 1.f;  // 3^x - 1
    s_val[((size_t)(tok >> 10) * 16 + h) * 1024 + (tok & 1023)] = sv;
  }
}

// ---------------- fused projection GEMMs (B^T form, f32 operands -> bf16 frags) ----
__global__ __launch_bounds__(256) void proj_kernel(
    const float* __restrict__ queries, const float* __restrict__ keys,
    const float* __restrict__ values, const float* __restrict__ Wq,
    const float* __restrict__ Wk, const float* __restrict__ Wv,
    u16* __restrict__ Qh, u16* __restrict__ Kh, u16* __restrict__ Vt) {
  int bid = blockIdx.x;
  const float *A, *Bm;
  int mb, nb, epi;
  if (bid < 256)      { A = queries; Bm = Wq;     mb = bid >> 4;          nb = bid & 15;          epi = 0; }
  else if (bid < 384) { A = keys;    Bm = Wk;     mb = (bid - 256) >> 3;  nb = (bid - 256) & 7;   epi = 1; }
  else                { A = Wv;      Bm = values; mb = (bid - 384) >> 5;  nb = (bid - 384) & 31;  epi = 2; }
  int lane = threadIdx.x & 63, w = threadIdx.x >> 6;
  int g = lane >> 4, cc = lane & 15;
  int mw = mb * 128 + (w >> 1) * 64;
  int nw = nb * 64 + (w & 1) * 32;
  f32x4 acc[4][2] = {};
  const float* Ab = A + (size_t)(mw + cc) * 1024 + g * 8;
  const float* Bb = Bm + (size_t)(nw + cc) * 1024 + g * 8;
  for (int kk = 0; kk < 1024; kk += 32) {
    bf16x8 af[4], bfr[2];
#pragma unroll
    for (int fm = 0; fm < 4; ++fm) af[fm] = f32frag(Ab + (size_t)fm * 16384 + kk);
#pragma unroll
    for (int fn = 0; fn < 2; ++fn) bfr[fn] = f32frag(Bb + (size_t)fn * 16384 + kk);
#pragma unroll
    for (int fm = 0; fm < 4; ++fm)
#pragma unroll
      for (int fn = 0; fn < 2; ++fn) acc[fm][fn] = MFMA16(af[fm], bfr[fn], acc[fm][fn]);
  }
#pragma unroll
  for (int fm = 0; fm < 4; ++fm)
#pragma unroll
    for (int fn = 0; fn < 2; ++fn)
#pragma unroll
      for (int r = 0; r < 4; ++r) {
        int row = mw + fm * 16 + 4 * g + r;
        int col = nw + fn * 16 + cc;
        u16 u = bf16b(acc[fm][fn][r]);
        if (epi == 0) {
          int b = row >> 10, l = row & 1023;
          Qh[((size_t)(b * 32 + (col >> 5)) * 1024 + l) * 32 + (col & 31)] = u;
        } else if (epi == 1) {
          int b = row >> 10, l = row & 1023;
          Kh[((size_t)(b * 16 + (col >> 5)) * 1024 + l) * 32 + (col & 31)] = u;
        } else {  // row = dv(0..511), col = token
          Vt[((size_t)(col >> 10) * 512 + row) * 1024 + (col & 1023)] = u;
        }
      }
}

// ---------------- z + PV + RMSNorm kernel ----------------
__global__ __launch_bounds__(256) void zpv_kernel(
    const u16* __restrict__ Qh, const u16* __restrict__ Kh, const u16* __restrict__ Vt,
    const float* __restrict__ lq1, const float* __restrict__ lk1,
    const float* __restrict__ lq2, const float* __restrict__ lk2,
    const float* __restrict__ gvec,
    float* __restrict__ iz0row, float* __restrict__ iz1row, float* __restrict__ izrow,
    u16* __restrict__ Vn) {
  __shared__ u16 Plds[4][1024];
  __shared__ float accbuf[4][1024];
  __shared__ float zlds0[4][16], zlds1[4][16], zalds[4][16];

  int rt = blockIdx.x, bh = blockIdx.y;
  int b = bh >> 4, h = bh & 15;
  int tid = threadIdx.x;
  int w = tid >> 6, lane = tid & 63, g = lane >> 4, cc = lane & 15;
  int i0 = rt * 16;
  const int nt = rt + 1;

  float d1 = 0.f, d2 = 0.f;
#pragma unroll
  for (int t = 0; t < 32; ++t) { d1 += lq1[t] * lk1[t]; d2 += lq2[t] * lk2[t]; }
  const float lam = __expf(d1) - __expf(d2) + LAMI;

  const u16* Ksg = Kh + (size_t)bh * 32768;
  const bf16x8 q0 = *(const bf16x8*)(Qh + ((size_t)(b * 32 + 2 * h) * 1024 + i0 + cc) * 32 + g * 8);
  const bf16x8 q1 = *(const bf16x8*)(Qh + ((size_t)(b * 32 + 2 * h + 1) * 1024 + i0 + cc) * 32 + g * 8);

  const f32x4 zf = {0.f, 0.f, 0.f, 0.f};
  const int iC = i0 + cc;

#define KFRAG(jt) (*(const bf16x8*)(Ksg + (size_t)((jt) * 16 + cc) * 32 + g * 8))

  // ---- phase A: z partials over this wave's jt subset ----
  float z0 = 0.f, z1 = 0.f;
  for (int jt = w; jt < nt; jt += 4) {
    bf16x8 kf = KFRAG(jt);
    f32x4 s0 = MFMA16(kf, q0, zf);  // S^T: row = key j, col = query i
    f32x4 s1 = MFMA16(kf, q1, zf);
#pragma unroll
    for (int r = 0; r < 4; ++r) {
      int j = jt * 16 + 4 * g + r;
      float e0 = exp2f(s0[r] * KEXP);
      float e1 = exp2f(s1[r] * KEXP);
      if (j <= iC) { z0 += e0; z1 += e1; }
    }
  }
  z0 += __shfl_xor(z0, 16); z0 += __shfl_xor(z0, 32);
  z1 += __shfl_xor(z1, 16); z1 += __shfl_xor(z1, 32);
  if (lane < 16) { zlds0[w][lane] = z0; zlds1[w][lane] = z1; }
  __syncthreads();
  float zz0 = zlds0[0][cc] + zlds0[1][cc] + zlds0[2][cc] + zlds0[3][cc];
  float zz1 = zlds1[0][cc] + zlds1[1][cc] + zlds1[2][cc] + zlds1[3][cc];
  const float iz0 = 1.f / zz0;
  const float iz1n = lam / zz1;
  if (w == 0 && lane < 16) {
    iz0row[(size_t)bh * 1024 + i0 + lane] = iz0;
    iz1row[(size_t)bh * 1024 + i0 + lane] = iz1n;
  }

  // ---- phase B: aw -> P -> PV partials; za partials ----
  f32x4 acc[4] = {zf, zf, zf, zf};
  float za = 0.f;
  const u16* Vb = Vt + (size_t)(b * 8 + (h >> 1)) * 65536;
  for (int jt0 = w; jt0 < nt; jt0 += 8) {
    int jt1 = jt0 + 4;
    bool pair = (jt1 < nt);
    {
      bf16x8 kf = KFRAG(jt0);
      f32x4 s0 = MFMA16(kf, q0, zf);
      f32x4 s1 = MFMA16(kf, q1, zf);
#pragma unroll
      for (int r = 0; r < 4; ++r) {
        int j = jt0 * 16 + 4 * g + r;
        float awv = exp2f(s0[r] * KEXP) * iz0 - exp2f(s1[r] * KEXP) * iz1n;
        bool ok = (j <= iC);
        za += ok ? exp2f(awv * LOG2E) : 0.f;
        int jl = 4 * g + r;
        Plds[w][cc * 64 + (jl ^ ((cc & 7) << 3))] = bf16b(ok ? awv : 0.f);
      }
    }
    if (pair) {
      bf16x8 kf = KFRAG(jt1);
      f32x4 s0 = MFMA16(kf, q0, zf);
      f32x4 s1 = MFMA16(kf, q1, zf);
#pragma unroll
      for (int r = 0; r < 4; ++r) {
        int j = jt1 * 16 + 4 * g + r;
        float awv = exp2f(s0[r] * KEXP) * iz0 - exp2f(s1[r] * KEXP) * iz1n;
        bool ok = (j <= iC);
        za += ok ? exp2f(awv * LOG2E) : 0.f;
        int jl = 16 + 4 * g + r;
        Plds[w][cc * 64 + (jl ^ ((cc & 7) << 3))] = bf16b(ok ? awv : 0.f);
      }
    } else {
#pragma unroll
      for (int r = 0; r < 4; ++r) {
        int jl = 16 + 4 * g + r;
        Plds[w][cc * 64 + (jl ^ ((cc & 7) << 3))] = 0;
      }
    }
    // intra-wave cross-lane LDS RAW: drain before read (lanes exchange data)
    asm volatile("s_waitcnt lgkmcnt(0)" ::: "memory");
    bf16x8 pa = *(const bf16x8*)&Plds[w][cc * 64 + ((8 * g) ^ ((cc & 7) << 3))];
    int jtsel = (g < 2) ? jt0 : (pair ? jt1 : jt0);
    int jb = jtsel * 16 + (g & 1) * 8;
#pragma unroll
    for (int ds = 0; ds < 4; ++ds) {
      bf16x8 vf = *(const bf16x8*)(Vb + (size_t)(ds * 16 + cc) * 1024 + jb);
      acc[ds] = MFMA16(pa, vf, acc[ds]);  // D[i][d]
    }
  }
  za += __shfl_xor(za, 16); za += __shfl_xor(za, 32);
  if (lane < 16) zalds[w][lane] = za;
#pragma unroll
  for (int ds = 0; ds < 4; ++ds)
#pragma unroll
    for (int r = 0; r < 4; ++r)
      accbuf[w][(4 * g + r) * 64 + ds * 16 + cc] = acc[ds][r];
  __syncthreads();

  if (w == 0 && lane < 16) {
    float zaf = zalds[0][lane] + zalds[1][lane] + zalds[2][lane] + zalds[3][lane];
    izrow[(size_t)bh * 1024 + i0 + lane] = 1.f / (zaf + (float)(1023 - (i0 + lane)));
  }

  // combine PV partials: wave w handles rows w*4 .. w*4+3; lane = col d
  float gl = gvec[lane];
#pragma unroll
  for (int rr = 0; rr < 4; ++rr) {
    int row = w * 4 + rr;
    float val = accbuf[0][row * 64 + lane] + accbuf[1][row * 64 + lane] +
                accbuf[2][row * 64 + lane] + accbuf[3][row * 64 + lane];
    float s = val * val;
    s += __shfl_xor(s, 1);  s += __shfl_xor(s, 2);  s += __shfl_xor(s, 4);
    s += __shfl_xor(s, 8);  s += __shfl_xor(s, 16); s += __shfl_xor(s, 32);
    float rs = rsqrtf(s * (1.f / 64.f) + 1e-5f) * ONEML;
    Vn[(size_t)(b * 1024 + i0 + row) * 1024 + h * 64 + lane] = bf16b(val * rs * gl);
  }
#undef KFRAG
}

// ---------------- series kernel: one wave per causal 16x16 tile ----------------
__global__ __launch_bounds__(256) void series_kernel(
    const u16* __restrict__ Qh, const u16* __restrict__ Kh,
    const float* __restrict__ iz0row, const float* __restrict__ iz1row,
    const float* __restrict__ izrow, float* __restrict__ series) {
  int bh = blockIdx.y;
  int b = bh >> 4, h = bh & 15;
  int w = threadIdx.x >> 6, lane = threadIdx.x & 63, g = lane >> 4, cc = lane & 15;
  int t = blockIdx.x * 4 + w;
  int rt = (int)((sqrtf((float)(8 * t + 1)) - 1.f) * 0.5f);
  int jt = t - ((rt * (rt + 1)) >> 1);
  if (jt > rt) { rt += 1; jt = t - ((rt * (rt + 1)) >> 1); }
  else if (jt < 0) { rt -= 1; jt = t - ((rt * (rt + 1)) >> 1); }
  int i0 = rt * 16, j0 = jt * 16;

  const u16* Ksg = Kh + (size_t)bh * 32768;
  const bf16x8 q0 = *(const bf16x8*)(Qh + ((size_t)(b * 32 + 2 * h) * 1024 + i0 + cc) * 32 + g * 8);
  const bf16x8 q1 = *(const bf16x8*)(Qh + ((size_t)(b * 32 + 2 * h + 1) * 1024 + i0 + cc) * 32 + g * 8);
  const bf16x8 kf = *(const bf16x8*)(Ksg + (size_t)(j0 + cc) * 32 + g * 8);
  const f32x4 zf = {0.f, 0.f, 0.f, 0.f};
  f32x4 s0 = MFMA16(q0, kf, zf);  // D[i][j]: row = i, col = j
  f32x4 s1 = MFMA16(q1, kf, zf);

  const float* izp0 = iz0row + (size_t)bh * 1024;
  const float* izp1 = iz1row + (size_t)bh * 1024;
  const float* izpa = izrow + (size_t)bh * 1024;
  float* srow = series + ((size_t)bh << 20);
  int j = j0 + cc;
#pragma unroll
  for (int r = 0; r < 4; ++r) {
    int irow = i0 + 4 * g + r;
    float iz0r = izp0[irow], iz1r = izp1[irow], izar = izpa[irow];
    float awv = exp2f(s0[r] * KEXP) * iz0r - exp2f(s1[r] * KEXP) * iz1r;
    float v = (j <= irow) ? exp2f(awv * LOG2E) * izar : izar;
    srow[(size_t)irow * 1024 + j] = v;
  }
}

// ---------------- streaming fill: prior + s (full) + series tail ----------------
__global__ __launch_bounds__(256) void fill_kernel(const float* __restrict__ s_val,
                                                   const float* __restrict__ izrow,
                                                   float* __restrict__ series,
                                                   float* __restrict__ prior,
                                                   float* __restrict__ sOut) {
  int bid = blockIdx.x;
  int bh = bid >> 7;
  int r0 = (bid & 127) * 8;
  int tid = threadIdx.x;
  int j0 = tid * 4;
  size_t hb = (size_t)bh << 20;
  const float* svp = s_val + (size_t)bh * 1024;
  const float* izp = izrow + (size_t)bh * 1024;
#pragma unroll 2
  for (int rr = 0; rr < 8; ++rr) {
    int i = r0 + rr;
    float sv = svp[i];
    float c1 = 0.3989422804014327f / sv;               // 1/(sqrt(2pi)*s)
    float c2 = -0.7213475204444817f / (sv * sv);       // -log2e/(2 s^2)
    size_t base = hb + (size_t)i * 1024;
    float4 pv;
    float dd;
    dd = (float)(i - j0);       pv.x = c1 * exp2f(c2 * dd * dd);
    dd = (float)(i - (j0 + 1)); pv.y = c1 * exp2f(c2 * dd * dd);
    dd = (float)(i - (j0 + 2)); pv.z = c1 * exp2f(c2 * dd * dd);
    dd = (float)(i - (j0 + 3)); pv.w = c1 * exp2f(c2 * dd * dd);
    *(float4*)(prior + base + j0) = pv;
    float4 s4 = {sv, sv, sv, sv};
    *(float4*)(sOut + base + j0) = s4;
    int jstart = (i >> 4) * 16 + 16;
    int j = jstart + j0;
    if (j < 1024) {
      float izv = izp[i];
      float4 f4 = {izv, izv, izv, izv};
      *(float4*)(series + base + j) = f4;
    }
  }
}

// ---------------- out = Vn @ Wo^T ----------------
__global__ __launch_bounds__(256) void wo_kernel(const u16* __restrict__ Vn,
                                                 const float* __restrict__ Wo,
                                                 float* __restrict__ out) {
  int bid = blockIdx.x;
  int mb = bid >> 4, nb = bid & 15;
  int lane = threadIdx.x & 63, w = threadIdx.x >> 6;
  int g = lane >> 4, cc = lane & 15;
  int mw = mb * 128 + (w >> 1) * 64;
  int nw = nb * 64 + (w & 1) * 32;
  f32x4 acc[4][2] = {};
  const u16* Ab = Vn + (size_t)(mw + cc) * 1024 + g * 8;
  const float* Bb = Wo + (size_t)(nw + cc) * 1024 + g * 8;
  for (int kk = 0; kk < 1024; kk += 32) {
    bf16x8 af[4], bfr[2];
#pragma unroll
    for (int fm = 0; fm < 4; ++fm) af[fm] = *(const bf16x8*)(Ab + (size_t)fm * 16384 + kk);
#pragma unroll
    for (int fn = 0; fn < 2; ++fn) bfr[fn] = f32frag(Bb + (size_t)fn * 16384 + kk);
#pragma unroll
    for (int fm = 0; fm < 4; ++fm)
#pragma unroll
      for (int fn = 0; fn < 2; ++fn) acc[fm][fn] = MFMA16(af[fm], bfr[fn], acc[fm][fn]);
  }
#pragma unroll
  for (int fm = 0; fm < 4; ++fm)
#pragma unroll
    for (int fn = 0; fn < 2; ++fn)
#pragma unroll
      for (int r = 0; r < 4; ++r) {
        int row = mw + fm * 16 + 4 * g + r;
        int col = nw + fn * 16 + cc;
        out[(size_t)row * 1024 + col] = acc[fm][fn][r];
      }
}

extern "C" void kernel_launch(void* const* d_in, const int* in_sizes, int n_in,
                              void* d_out, int out_size, void* d_ws, size_t ws_size,
                              hipStream_t stream) {
  (void)in_sizes; (void)n_in; (void)out_size; (void)ws_size;
  const float* queries = (const float*)d_in[0];
  const float* keys    = (const float*)d_in[1];
  const float* values  = (const float*)d_in[2];
  const float* Wq   = (const float*)d_in[4];
  const float* Wk   = (const float*)d_in[5];
  const float* Wv   = (const float*)d_in[6];
  const float* Wo   = (const float*)d_in[7];
  const float* Ws   = (const float*)d_in[8];
  const float* bsig = (const float*)d_in[9];
  const float* lq1  = (const float*)d_in[10];
  const float* lk1  = (const float*)d_in[11];
  const float* lq2  = (const float*)d_in[12];
  const float* lk2  = (const float*)d_in[13];
  const float* gvec = (const float*)d_in[14];

  float* out0       = (float*)d_out;
  float* out_series = out0 + 2097152;
  float* out_prior  = out_series + 33554432;
  float* out_s      = out_prior + 33554432;

  char* ws = (char*)d_ws;
  u16*  Qh     = (u16*)(ws);                       // [2,32,1024,32] bf16, 4MB
  u16*  Kh     = (u16*)(ws + (4ull << 20));        // [2,16,1024,32] bf16, 2MB
  u16*  Vt     = (u16*)(ws + (6ull << 20));        // [2,8,64dv,1024] bf16, 2MB
  u16*  Vn     = (u16*)(ws + (8ull << 20));        // [2048,1024]    bf16, 4MB
  float* s_val  = (float*)(ws + (12ull << 20));    // [2,16,1024] f32
  float* izrow  = (float*)(ws + (13ull << 20));    // [2,16,1024] f32
  float* iz0row = (float*)(ws + (14ull << 20));    // [2,16,1024] f32
  float* iz1row = (float*)(ws + (15ull << 20));    // [2,16,1024] f32

  sigma_kernel<<<2048, 256, 0, stream>>>(queries, Ws, bsig, s_val);
  // ---- ATTRIBUTION EXPERIMENT: proj x3 (idempotent), fill x2 (idempotent) ----
  // delta vs single-launch baseline = 2*proj + fill. Decode:
  // ~+110 -> whale is zpv+series; ~+200 -> whale is fill; ~+470 -> whale is proj.
  proj_kernel<<<512, 256, 0, stream>>>(queries, keys, values, Wq, Wk, Wv, Qh, Kh, Vt);
  proj_kernel<<<512, 256, 0, stream>>>(queries, keys, values, Wq, Wk, Wv, Qh, Kh, Vt);
  proj_kernel<<<512, 256, 0, stream>>>(queries, keys, values, Wq, Wk, Wv, Qh, Kh, Vt);
  zpv_kernel<<<dim3(64, 32), 256, 0, stream>>>(Qh, Kh, Vt, lq1, lk1, lq2, lk2, gvec,
                                               iz0row, iz1row, izrow, Vn);
  series_kernel<<<dim3(520, 32), 256, 0, stream>>>(Qh, Kh, iz0row, iz1row, izrow,
                                                   out_series);
  wo_kernel<<<256, 256, 0, stream>>>(Vn, Wo, out0);
  fill_kernel<<<4096, 256, 0, stream>>>(s_val, izrow, out_series, out_prior, out_s);
  fill_kernel<<<4096, 256, 0, stream>>>(s_val, izrow, out_series, out_prior, out_s);
}

// Round 6
// 276.657 us; speedup vs baseline: 1.8759x; 1.8759x over previous
//
#include <hip/hip_runtime.h>

typedef __bf16 bf16x8 __attribute__((ext_vector_type(8)));
typedef float f32x4 __attribute__((ext_vector_type(4)));
typedef unsigned int u32x4 __attribute__((ext_vector_type(4)));
typedef unsigned short u16;

#define MFMA16(A, B, C) __builtin_amdgcn_mfma_f32_16x16x32_bf16((A), (B), (C), 0, 0, 0)

#define KEXP   (0.17677669529663687f * 1.4426950408889634f)
#define LOG2E  1.4426950408889634f
#define LAMI   0.35550906759096926f           // LAMBDA_INIT = 0.8 - 0.6*exp(-0.3)
#define ONEML  0.6444909324090307f            // 1 - LAMBDA_INIT

static __device__ __forceinline__ u16 bf16b(float v) {
  __bf16 b = (__bf16)v;
  return __builtin_bit_cast(u16, b);
}

static __device__ __forceinline__ bf16x8 f32frag(const float* p) {
  float4 a = *(const float4*)p;
  float4 b = *(const float4*)(p + 4);
  bf16x8 r;
  r[0] = (__bf16)a.x; r[1] = (__bf16)a.y; r[2] = (__bf16)a.z; r[3] = (__bf16)a.w;
  r[4] = (__bf16)b.x; r[5] = (__bf16)b.y; r[6] = (__bf16)b.z; r[7] = (__bf16)b.w;
  return r;
}

// ---------------- sigma -> s_val [B,H,L] ----------------
__global__ __launch_bounds__(256) void sigma_kernel(const float* __restrict__ q,
                                                    const float* __restrict__ Ws,
                                                    const float* __restrict__ bsig,
                                                    float* __restrict__ s_val) {
  int tok = blockIdx.x;
  int h = threadIdx.x >> 4;
  int l = threadIdx.x & 15;
  const float* qr = q + (size_t)tok * 1024;
  const float* wr = Ws + (size_t)h * 1024;
  float acc = 0.f;
#pragma unroll 4
  for (int c = 0; c < 16; ++c) {
    float4 a = *(const float4*)(qr + c * 64 + l * 4);
    float4 b = *(const float4*)(wr + c * 64 + l * 4);
    acc += a.x * b.x + a.y * b.y + a.z * b.z + a.w * b.w;
  }
  acc += __shfl_xor(acc, 1); acc += __shfl_xor(acc, 2);
  acc += __shfl_xor(acc, 4); acc += __shfl_xor(acc, 8);
  if (l == 0) {
    float sg = acc + bsig[h];
    float sig = 1.f / (1.f + __expf(-5.f * sg));
    float sv = exp2f(1.5849625007211562f * (sig + 1e-5f)) - 1.f;  // 3^x - 1
    s_val[((size_t)(tok >> 10) * 16 + h) * 1024 + (tok & 1023)] = sv;
  }
}

// ---------------- fused projection GEMMs (B^T form, f32 operands -> bf16 frags) ----
__global__ __launch_bounds__(256) void proj_kernel(
    const float* __restrict__ queries, const float* __restrict__ keys,
    const float* __restrict__ values, const float* __restrict__ Wq,
    const float* __restrict__ Wk, const float* __restrict__ Wv,
    u16* __restrict__ Qh, u16* __restrict__ Kh, u16* __restrict__ Vt) {
  int bid = blockIdx.x;
  const float *A, *Bm;
  int mb, nb, epi;
  if (bid < 256)      { A = queries; Bm = Wq;     mb = bid >> 4;          nb = bid & 15;          epi = 0; }
  else if (bid < 384) { A = keys;    Bm = Wk;     mb = (bid - 256) >> 3;  nb = (bid - 256) & 7;   epi = 1; }
  else                { A = Wv;      Bm = values; mb = (bid - 384) >> 5;  nb = (bid - 384) & 31;  epi = 2; }
  int lane = threadIdx.x & 63, w = threadIdx.x >> 6;
  int g = lane >> 4, cc = lane & 15;
  int mw = mb * 128 + (w >> 1) * 64;
  int nw = nb * 64 + (w & 1) * 32;
  f32x4 acc[4][2] = {};
  const float* Ab = A + (size_t)(mw + cc) * 1024 + g * 8;
  const float* Bb = Bm + (size_t)(nw + cc) * 1024 + g * 8;
  for (int kk = 0; kk < 1024; kk += 32) {
    bf16x8 af[4], bfr[2];
#pragma unroll
    for (int fm = 0; fm < 4; ++fm) af[fm] = f32frag(Ab + (size_t)fm * 16384 + kk);
#pragma unroll
    for (int fn = 0; fn < 2; ++fn) bfr[fn] = f32frag(Bb + (size_t)fn * 16384 + kk);
#pragma unroll
    for (int fm = 0; fm < 4; ++fm)
#pragma unroll
      for (int fn = 0; fn < 2; ++fn) acc[fm][fn] = MFMA16(af[fm], bfr[fn], acc[fm][fn]);
  }
#pragma unroll
  for (int fm = 0; fm < 4; ++fm)
#pragma unroll
    for (int fn = 0; fn < 2; ++fn)
#pragma unroll
      for (int r = 0; r < 4; ++r) {
        int row = mw + fm * 16 + 4 * g + r;
        int col = nw + fn * 16 + cc;
        u16 u = bf16b(acc[fm][fn][r]);
        if (epi == 0) {
          int b = row >> 10, l = row & 1023;
          Qh[((size_t)(b * 32 + (col >> 5)) * 1024 + l) * 32 + (col & 31)] = u;
        } else if (epi == 1) {
          int b = row >> 10, l = row & 1023;
          Kh[((size_t)(b * 16 + (col >> 5)) * 1024 + l) * 32 + (col & 31)] = u;
        } else {  // row = dv(0..511), col = token
          Vt[((size_t)(col >> 10) * 512 + row) * 1024 + (col & 1023)] = u;
        }
      }
}

// ---------------- z + PV + RMSNorm kernel ----------------
__global__ __launch_bounds__(256) void zpv_kernel(
    const u16* __restrict__ Qh, const u16* __restrict__ Kh, const u16* __restrict__ Vt,
    const float* __restrict__ lq1, const float* __restrict__ lk1,
    const float* __restrict__ lq2, const float* __restrict__ lk2,
    const float* __restrict__ gvec,
    float* __restrict__ iz0row, float* __restrict__ iz1row, float* __restrict__ izrow,
    u16* __restrict__ Vn) {
  __shared__ u16 Plds[4][1024];
  __shared__ float accbuf[4][1024];
  __shared__ float zlds0[4][16], zlds1[4][16], zalds[4][16];

  int rt = blockIdx.x, bh = blockIdx.y;
  int b = bh >> 4, h = bh & 15;
  int tid = threadIdx.x;
  int w = tid >> 6, lane = tid & 63, g = lane >> 4, cc = lane & 15;
  int i0 = rt * 16;
  const int nt = rt + 1;

  float d1 = 0.f, d2 = 0.f;
#pragma unroll
  for (int t = 0; t < 32; ++t) { d1 += lq1[t] * lk1[t]; d2 += lq2[t] * lk2[t]; }
  const float lam = __expf(d1) - __expf(d2) + LAMI;

  const u16* Ksg = Kh + (size_t)bh * 32768;
  const bf16x8 q0 = *(const bf16x8*)(Qh + ((size_t)(b * 32 + 2 * h) * 1024 + i0 + cc) * 32 + g * 8);
  const bf16x8 q1 = *(const bf16x8*)(Qh + ((size_t)(b * 32 + 2 * h + 1) * 1024 + i0 + cc) * 32 + g * 8);

  const f32x4 zf = {0.f, 0.f, 0.f, 0.f};
  const int iC = i0 + cc;

#define KFRAG(jt) (*(const bf16x8*)(Ksg + (size_t)((jt) * 16 + cc) * 32 + g * 8))

  // ---- phase A: z partials over this wave's jt subset ----
  float z0 = 0.f, z1 = 0.f;
  for (int jt = w; jt < nt; jt += 4) {
    bf16x8 kf = KFRAG(jt);
    f32x4 s0 = MFMA16(kf, q0, zf);  // S^T: row = key j, col = query i
    f32x4 s1 = MFMA16(kf, q1, zf);
#pragma unroll
    for (int r = 0; r < 4; ++r) {
      int j = jt * 16 + 4 * g + r;
      float e0 = exp2f(s0[r] * KEXP);
      float e1 = exp2f(s1[r] * KEXP);
      if (j <= iC) { z0 += e0; z1 += e1; }
    }
  }
  z0 += __shfl_xor(z0, 16); z0 += __shfl_xor(z0, 32);
  z1 += __shfl_xor(z1, 16); z1 += __shfl_xor(z1, 32);
  if (lane < 16) { zlds0[w][lane] = z0; zlds1[w][lane] = z1; }
  __syncthreads();
  float zz0 = zlds0[0][cc] + zlds0[1][cc] + zlds0[2][cc] + zlds0[3][cc];
  float zz1 = zlds1[0][cc] + zlds1[1][cc] + zlds1[2][cc] + zlds1[3][cc];
  const float iz0 = 1.f / zz0;
  const float iz1n = lam / zz1;
  if (w == 0 && lane < 16) {
    iz0row[(size_t)bh * 1024 + i0 + lane] = iz0;
    iz1row[(size_t)bh * 1024 + i0 + lane] = iz1n;
  }

  // ---- phase B: aw -> P -> PV partials; za partials ----
  f32x4 acc[4] = {zf, zf, zf, zf};
  float za = 0.f;
  const u16* Vb = Vt + (size_t)(b * 8 + (h >> 1)) * 65536;
  for (int jt0 = w; jt0 < nt; jt0 += 8) {
    int jt1 = jt0 + 4;
    bool pair = (jt1 < nt);
    {
      bf16x8 kf = KFRAG(jt0);
      f32x4 s0 = MFMA16(kf, q0, zf);
      f32x4 s1 = MFMA16(kf, q1, zf);
#pragma unroll
      for (int r = 0; r < 4; ++r) {
        int j = jt0 * 16 + 4 * g + r;
        float awv = exp2f(s0[r] * KEXP) * iz0 - exp2f(s1[r] * KEXP) * iz1n;
        bool ok = (j <= iC);
        za += ok ? exp2f(awv * LOG2E) : 0.f;
        int jl = 4 * g + r;
        Plds[w][cc * 64 + (jl ^ ((cc & 7) << 3))] = bf16b(ok ? awv : 0.f);
      }
    }
    if (pair) {
      bf16x8 kf = KFRAG(jt1);
      f32x4 s0 = MFMA16(kf, q0, zf);
      f32x4 s1 = MFMA16(kf, q1, zf);
#pragma unroll
      for (int r = 0; r < 4; ++r) {
        int j = jt1 * 16 + 4 * g + r;
        float awv = exp2f(s0[r] * KEXP) * iz0 - exp2f(s1[r] * KEXP) * iz1n;
        bool ok = (j <= iC);
        za += ok ? exp2f(awv * LOG2E) : 0.f;
        int jl = 16 + 4 * g + r;
        Plds[w][cc * 64 + (jl ^ ((cc & 7) << 3))] = bf16b(ok ? awv : 0.f);
      }
    } else {
#pragma unroll
      for (int r = 0; r < 4; ++r) {
        int jl = 16 + 4 * g + r;
        Plds[w][cc * 64 + (jl ^ ((cc & 7) << 3))] = 0;
      }
    }
    // intra-wave cross-lane LDS RAW: drain before read (lanes exchange data)
    asm volatile("s_waitcnt lgkmcnt(0)" ::: "memory");
    bf16x8 pa = *(const bf16x8*)&Plds[w][cc * 64 + ((8 * g) ^ ((cc & 7) << 3))];
    int jtsel = (g < 2) ? jt0 : (pair ? jt1 : jt0);
    int jb = jtsel * 16 + (g & 1) * 8;
#pragma unroll
    for (int ds = 0; ds < 4; ++ds) {
      bf16x8 vf = *(const bf16x8*)(Vb + (size_t)(ds * 16 + cc) * 1024 + jb);
      acc[ds] = MFMA16(pa, vf, acc[ds]);  // D[i][d]
    }
  }
  za += __shfl_xor(za, 16); za += __shfl_xor(za, 32);
  if (lane < 16) zalds[w][lane] = za;
#pragma unroll
  for (int ds = 0; ds < 4; ++ds)
#pragma unroll
    for (int r = 0; r < 4; ++r)
      accbuf[w][(4 * g + r) * 64 + ds * 16 + cc] = acc[ds][r];
  __syncthreads();

  if (w == 0 && lane < 16) {
    float zaf = zalds[0][lane] + zalds[1][lane] + zalds[2][lane] + zalds[3][lane];
    izrow[(size_t)bh * 1024 + i0 + lane] = 1.f / (zaf + (float)(1023 - (i0 + lane)));
  }

  // combine PV partials: wave w handles rows w*4 .. w*4+3; lane = col d
  float gl = gvec[lane];
#pragma unroll
  for (int rr = 0; rr < 4; ++rr) {
    int row = w * 4 + rr;
    float val = accbuf[0][row * 64 + lane] + accbuf[1][row * 64 + lane] +
                accbuf[2][row * 64 + lane] + accbuf[3][row * 64 + lane];
    float s = val * val;
    s += __shfl_xor(s, 1);  s += __shfl_xor(s, 2);  s += __shfl_xor(s, 4);
    s += __shfl_xor(s, 8);  s += __shfl_xor(s, 16); s += __shfl_xor(s, 32);
    float rs = rsqrtf(s * (1.f / 64.f) + 1e-5f) * ONEML;
    Vn[(size_t)(b * 1024 + i0 + row) * 1024 + h * 64 + lane] = bf16b(val * rs * gl);
  }
#undef KFRAG
}

// ---------------- series kernel: one wave per causal 16x16 tile ----------------
__global__ __launch_bounds__(256) void series_kernel(
    const u16* __restrict__ Qh, const u16* __restrict__ Kh,
    const float* __restrict__ iz0row, const float* __restrict__ iz1row,
    const float* __restrict__ izrow, float* __restrict__ series) {
  int bh = blockIdx.y;
  int b = bh >> 4, h = bh & 15;
  int w = threadIdx.x >> 6, lane = threadIdx.x & 63, g = lane >> 4, cc = lane & 15;
  int t = blockIdx.x * 4 + w;
  int rt = (int)((sqrtf((float)(8 * t + 1)) - 1.f) * 0.5f);
  int jt = t - ((rt * (rt + 1)) >> 1);
  if (jt > rt) { rt += 1; jt = t - ((rt * (rt + 1)) >> 1); }
  else if (jt < 0) { rt -= 1; jt = t - ((rt * (rt + 1)) >> 1); }
  int i0 = rt * 16, j0 = jt * 16;

  const u16* Ksg = Kh + (size_t)bh * 32768;
  const bf16x8 q0 = *(const bf16x8*)(Qh + ((size_t)(b * 32 + 2 * h) * 1024 + i0 + cc) * 32 + g * 8);
  const bf16x8 q1 = *(const bf16x8*)(Qh + ((size_t)(b * 32 + 2 * h + 1) * 1024 + i0 + cc) * 32 + g * 8);
  const bf16x8 kf = *(const bf16x8*)(Ksg + (size_t)(j0 + cc) * 32 + g * 8);
  const f32x4 zf = {0.f, 0.f, 0.f, 0.f};
  f32x4 s0 = MFMA16(q0, kf, zf);  // D[i][j]: row = i, col = j
  f32x4 s1 = MFMA16(q1, kf, zf);

  const float* izp0 = iz0row + (size_t)bh * 1024;
  const float* izp1 = iz1row + (size_t)bh * 1024;
  const float* izpa = izrow + (size_t)bh * 1024;
  float* srow = series + ((size_t)bh << 20);
  int j = j0 + cc;
#pragma unroll
  for (int r = 0; r < 4; ++r) {
    int irow = i0 + 4 * g + r;
    float iz0r = izp0[irow], iz1r = izp1[irow], izar = izpa[irow];
    float awv = exp2f(s0[r] * KEXP) * iz0r - exp2f(s1[r] * KEXP) * iz1r;
    float v = (j <= irow) ? exp2f(awv * LOG2E) * izar : izar;
    srow[(size_t)irow * 1024 + j] = v;
  }
}

// ---------------- streaming fill: prior + s (full) + series tail ----------------
// memset-shaped: one block per (bh,row), no loops, 1 f32x4 nt-store per
// thread per array. 32768 blocks x 256 thr.
__global__ __launch_bounds__(256) void fill_kernel(const float* __restrict__ s_val,
                                                   const float* __restrict__ izrow,
                                                   float* __restrict__ series,
                                                   float* __restrict__ prior,
                                                   float* __restrict__ sOut) {
  int bid = blockIdx.x;          // 32768 = 32 bh * 1024 rows
  int bh = bid >> 10;
  int i  = bid & 1023;
  int j0 = threadIdx.x * 4;
  size_t base = ((size_t)bh << 20) + (size_t)i * 1024;
  float sv = s_val[(size_t)bh * 1024 + i];
  float c1 = 0.3989422804014327f / sv;               // 1/(sqrt(2pi)*s)
  float c2 = -0.7213475204444817f / (sv * sv);       // -log2e/(2 s^2)
  f32x4 pv;
  float dd;
  dd = (float)(i - j0);       pv.x = c1 * exp2f(c2 * dd * dd);
  dd = (float)(i - (j0 + 1)); pv.y = c1 * exp2f(c2 * dd * dd);
  dd = (float)(i - (j0 + 2)); pv.z = c1 * exp2f(c2 * dd * dd);
  dd = (float)(i - (j0 + 3)); pv.w = c1 * exp2f(c2 * dd * dd);
  __builtin_nontemporal_store(pv, (f32x4*)(prior + base + j0));
  f32x4 s4 = {sv, sv, sv, sv};
  __builtin_nontemporal_store(s4, (f32x4*)(sOut + base + j0));
  // series tail: [align16(i)+16, 1024) = constant 1/ZA
  int j = ((i >> 4) * 16 + 16) + j0;
  if (j < 1024) {
    float izv = izrow[(size_t)bh * 1024 + i];
    f32x4 f4 = {izv, izv, izv, izv};
    __builtin_nontemporal_store(f4, (f32x4*)(series + base + j));
  }
}

// ---------------- out = Vn @ Wo^T ----------------
__global__ __launch_bounds__(256) void wo_kernel(const u16* __restrict__ Vn,
                                                 const float* __restrict__ Wo,
                                                 float* __restrict__ out) {
  int bid = blockIdx.x;
  int mb = bid >> 4, nb = bid & 15;
  int lane = threadIdx.x & 63, w = threadIdx.x >> 6;
  int g = lane >> 4, cc = lane & 15;
  int mw = mb * 128 + (w >> 1) * 64;
  int nw = nb * 64 + (w & 1) * 32;
  f32x4 acc[4][2] = {};
  const u16* Ab = Vn + (size_t)(mw + cc) * 1024 + g * 8;
  const float* Bb = Wo + (size_t)(nw + cc) * 1024 + g * 8;
  for (int kk = 0; kk < 1024; kk += 32) {
    bf16x8 af[4], bfr[2];
#pragma unroll
    for (int fm = 0; fm < 4; ++fm) af[fm] = *(const bf16x8*)(Ab + (size_t)fm * 16384 + kk);
#pragma unroll
    for (int fn = 0; fn < 2; ++fn) bfr[fn] = f32frag(Bb + (size_t)fn * 16384 + kk);
#pragma unroll
    for (int fm = 0; fm < 4; ++fm)
#pragma unroll
      for (int fn = 0; fn < 2; ++fn) acc[fm][fn] = MFMA16(af[fm], bfr[fn], acc[fm][fn]);
  }
#pragma unroll
  for (int fm = 0; fm < 4; ++fm)
#pragma unroll
    for (int fn = 0; fn < 2; ++fn)
#pragma unroll
      for (int r = 0; r < 4; ++r) {
        int row = mw + fm * 16 + 4 * g + r;
        int col = nw + fn * 16 + cc;
        out[(size_t)row * 1024 + col] = acc[fm][fn][r];
      }
}

extern "C" void kernel_launch(void* const* d_in, const int* in_sizes, int n_in,
                              void* d_out, int out_size, void* d_ws, size_t ws_size,
                              hipStream_t stream) {
  (void)in_sizes; (void)n_in; (void)out_size; (void)ws_size;
  const float* queries = (const float*)d_in[0];
  const float* keys    = (const float*)d_in[1];
  const float* values  = (const float*)d_in[2];
  const float* Wq   = (const float*)d_in[4];
  const float* Wk   = (const float*)d_in[5];
  const float* Wv   = (const float*)d_in[6];
  const float* Wo   = (const float*)d_in[7];
  const float* Ws   = (const float*)d_in[8];
  const float* bsig = (const float*)d_in[9];
  const float* lq1  = (const float*)d_in[10];
  const float* lk1  = (const float*)d_in[11];
  const float* lq2  = (const float*)d_in[12];
  const float* lk2  = (const float*)d_in[13];
  const float* gvec = (const float*)d_in[14];

  float* out0       = (float*)d_out;
  float* out_series = out0 + 2097152;
  float* out_prior  = out_series + 33554432;
  float* out_s      = out_prior + 33554432;

  char* ws = (char*)d_ws;
  u16*  Qh     = (u16*)(ws);                       // [2,32,1024,32] bf16, 4MB
  u16*  Kh     = (u16*)(ws + (4ull << 20));        // [2,16,1024,32] bf16, 2MB
  u16*  Vt     = (u16*)(ws + (6ull << 20));        // [2,8,64dv,1024] bf16, 2MB
  u16*  Vn     = (u16*)(ws + (8ull << 20));        // [2048,1024]    bf16, 4MB
  float* s_val  = (float*)(ws + (12ull << 20));    // [2,16,1024] f32
  float* izrow  = (float*)(ws + (13ull << 20));    // [2,16,1024] f32
  float* iz0row = (float*)(ws + (14ull << 20));    // [2,16,1024] f32
  float* iz1row = (float*)(ws + (15ull << 20));    // [2,16,1024] f32

  sigma_kernel<<<2048, 256, 0, stream>>>(queries, Ws, bsig, s_val);
  proj_kernel<<<512, 256, 0, stream>>>(queries, keys, values, Wq, Wk, Wv, Qh, Kh, Vt);
  zpv_kernel<<<dim3(64, 32), 256, 0, stream>>>(Qh, Kh, Vt, lq1, lk1, lq2, lk2, gvec,
                                               iz0row, iz1row, izrow, Vn);
  series_kernel<<<dim3(520, 32), 256, 0, stream>>>(Qh, Kh, iz0row, iz1row, izrow,
                                                   out_series);
  wo_kernel<<<256, 256, 0, stream>>>(Vn, Wo, out0);
  fill_kernel<<<32768, 256, 0, stream>>>(s_val, izrow, out_series, out_prior, out_s);
}